// Round 10
// baseline (811.232 us; speedup 1.0000x reference)
//
#include <hip/hip_runtime.h>
#include <hip/hip_bf16.h>

#define BB 512
#define TT 256

typedef __attribute__((ext_vector_type(8))) short bf16x8;
typedef __attribute__((ext_vector_type(4))) float f32x4;

__device__ __forceinline__ unsigned short f2b(float f) {
    union { float f; unsigned u; } v; v.f = f;
    unsigned r = v.u + 0x7FFFu + ((v.u >> 16) & 1u);
    return (unsigned short)(r >> 16);
}
__device__ __forceinline__ float b2f(unsigned short h) {
    union { unsigned u; float f; } v; v.u = ((unsigned)h) << 16;
    return v.f;
}
// packed f32x2 -> bf16x2 (v_cvt_pk_bf16_f32, RNE — bit-compatible with f2b)
__device__ __forceinline__ ushort2 pk2(float a, float b) {
    __hip_bfloat162 h = __float22bfloat162_rn(float2{a, b});
    union { __hip_bfloat162 h; ushort2 u; } v; v.h = h; return v.u;
}

// ---------------- fp32 -> bf16 convert (x input, linear layout) ----------------
__global__ __launch_bounds__(256) void cvt_kernel(const float* __restrict__ x,
                                                  unsigned short* __restrict__ xb, int n4) {
    int i = blockIdx.x * 256 + threadIdx.x;
    if (i >= n4) return;
    float4 v = reinterpret_cast<const float4*>(x)[i];
    ushort2 lo = pk2(v.x, v.y), hi = pk2(v.z, v.w);
    ushort4 o; o.x = lo.x; o.y = lo.y; o.z = hi.x; o.w = hi.y;
    reinterpret_cast<ushort4*>(xb)[i] = o;
}

// ---------------- input-projection GEMM (operand-swapped) ----------------
// D = W^T · x^T. XP out tile (s,t,ntg) at ((s*TT+t)*(N/16)+ntg)*256, elem
// lane*4+reg = (batch l15, col ntg*16+quad*4+reg).
// TG=8 t-rows per block (was 4): halves the per-block W stage overhead.
// TILED=0: A linear [b][t][k]; TILED=1: A tile-layout (prev rec output).
template<int K, int N, int TILED>
__global__ __launch_bounds__(256, 2) void gemm_xp(const unsigned short* __restrict__ A,
                                                  const float* __restrict__ W,
                                                  const float* __restrict__ bias,
                                                  unsigned short* __restrict__ XP) {
    constexpr int NT = N / 64;
    constexpr int KC = K / 32;
    constexpr int TG = 8;
    __shared__ unsigned short WT[N * K];
    const int tid = threadIdx.x;
    for (int idx = tid; idx < K * N; idx += 256) {
        int k = idx / N, n = idx % N;
        int ch = k >> 3;
        WT[n * K + (((ch ^ (n & 7)) << 3) | (k & 7))] = f2b(W[idx]);
    }
    __syncthreads();
    const int s   = blockIdx.x >> 5;          // 0..31 b-slice
    const int t4  = blockIdx.x & 31;          // 0..31 t-group (TG t's)
    const int w   = tid >> 6;
    const int lane = tid & 63;
    const int l15 = lane & 15;
    const int quad = lane >> 4;

    f32x4 acc[TG][NT];
#pragma unroll
    for (int mt = 0; mt < TG; ++mt)
#pragma unroll
        for (int nt = 0; nt < NT; ++nt) acc[mt][nt] = (f32x4)(0.0f);

#pragma unroll
    for (int kc = 0; kc < KC; ++kc) {
        bf16x8 bfr[NT];
        const int ch = kc * 4 + quad;
#pragma unroll
        for (int nt = 0; nt < NT; ++nt) {
            int n = w * (N / 4) + nt * 16 + l15;
            bfr[nt] = *reinterpret_cast<const bf16x8*>(&WT[n * K + ((ch ^ (n & 7)) << 3)]);
        }
#pragma unroll
        for (int mt = 0; mt < TG; ++mt) {
            int t = t4 * TG + mt;
            bf16x8 bf;
            if (TILED) {
                const unsigned short* tp =
                    &A[(((size_t)(s * TT + t) * (K / 16)) + kc * 2 + (quad >> 1)) * 256];
                int e = ((quad & 1) * 32 + l15) * 4;
                union { ushort4 u4[2]; bf16x8 v; } u;
                u.u4[0] = *reinterpret_cast<const ushort4*>(&tp[e]);
                u.u4[1] = *reinterpret_cast<const ushort4*>(&tp[e + 64]);
                bf = u.v;
            } else {
                int row = (s * 16 + l15) * TT + t;
                bf = *reinterpret_cast<const bf16x8*>(&A[(size_t)row * K + kc * 32 + quad * 8]);
            }
#pragma unroll
            for (int nt = 0; nt < NT; ++nt)
                acc[mt][nt] = __builtin_amdgcn_mfma_f32_16x16x32_bf16(bfr[nt], bf, acc[mt][nt], 0, 0, 0);
        }
    }
#pragma unroll
    for (int mt = 0; mt < TG; ++mt) {
        int t = t4 * TG + mt;
#pragma unroll
        for (int nt = 0; nt < NT; ++nt) {
            int ntg = w * NT + nt;
            float4 bv = reinterpret_cast<const float4*>(bias)[ntg * 4 + quad];
            size_t base = ((size_t)(s * TT + t) * (N / 16) + ntg) * 256;
            ushort2 lo = pk2(acc[mt][nt][0] + bv.x, acc[mt][nt][1] + bv.y);
            ushort2 hi = pk2(acc[mt][nt][2] + bv.z, acc[mt][nt][3] + bv.w);
            ushort4 o; o.x = lo.x; o.y = lo.y; o.z = hi.x; o.w = hi.y;
            *reinterpret_cast<ushort4*>(&XP[base + (size_t)lane * 4]) = o;
        }
    }
}

// ---------------- recurrence: h_t = relu(xp_t + h_{t-1} @ Wh) ----------------
// 512 threads = 2 batch-slices per block (waves 0-3 slice A, 4-7 slice B):
// 2 waves per SIMD -> the ds_read->MFMA->pack->ds_write chain of one slice
// overlaps the other's stalls (round-9 profile: ~800 cyc/step exposed latency
// at 1 wave/SIMD). Per-slice state fully independent (own LDS ping-pong).
// h in B-fragment-ready LDS layout: addr(b,k) = (k>>3)*128 + b*8 + (k&7).
// Strength-reduced XP/Hout pointers; two xp reg buffers reloaded 2 ahead.
// Barrier = builtin lgkm-only waitcnt + s_barrier (no vmcnt drain).
template<int H>
__global__ __launch_bounds__(512, 1) void rec_cp(const unsigned short* __restrict__ XP,
                                                 const float* __restrict__ Wh,
                                                 unsigned short* __restrict__ Hout) {
    constexpr int KC  = H / 32;
    constexpr int MT  = H / 64;
    constexpr int STR = (H / 16) * 256;   // shorts per time-step of XP/Hout
    __shared__ __align__(16) unsigned short hbuf[2][2][16 * H];  // [slice][pp][..]
    const int tid = threadIdx.x;
    const int sl = tid >> 8;               // slice within block
    const int s = blockIdx.x * 2 + sl;     // b-slice 0..31
    const int w = (tid >> 6) & 3;
    const int lane = tid & 63;
    const int l15 = lane & 15;
    const int quad = lane >> 4;
    const int colbase = w * (H / 4);

    // one-time: Wh^T A-fragments (fp32 global -> bf16)
    bf16x8 wh[KC][MT];
#pragma unroll
    for (int kc = 0; kc < KC; ++kc)
#pragma unroll
        for (int mt = 0; mt < MT; ++mt) {
            int m = colbase + mt * 16 + l15;
#pragma unroll
            for (int j = 0; j < 8; ++j)
                wh[kc][mt][j] = (short)f2b(Wh[(kc * 32 + quad * 8 + j) * H + m]);
        }

    for (int i = tid; i < 2 * 2 * 16 * H; i += 512)
        (&hbuf[0][0][0])[i] = 0;
    __syncthreads();

    const unsigned short* XPs = XP + (size_t)s * TT * STR;
    unsigned short* Houts = Hout + (size_t)s * TT * STR;

    // LDS offsets (shorts), constant all steps:
    const int rdo = quad * 128 + l15 * 8;                                        // af base
    const int wro = ((colbase >> 3) + (quad >> 1)) * 128 + l15 * 8 + (quad & 1) * 4;  // h write base
    const unsigned short* hr0 = &hbuf[sl][0][0];
    const unsigned short* hr1 = &hbuf[sl][1][0];
    unsigned short* hw0 = &hbuf[sl][0][0];
    unsigned short* hw1 = &hbuf[sl][1][0];

    // xp regs hold t=0 (A) and t=1 (B); pointers aim at t=2 / t=3.
    ushort4 xpA[MT], xpB[MT];
#pragma unroll
    for (int mt = 0; mt < MT; ++mt) {
        xpA[mt] = *reinterpret_cast<const ushort4*>(&XPs[(w * MT + mt) * 256 + lane * 4]);
        xpB[mt] = *reinterpret_cast<const ushort4*>(&XPs[STR + (w * MT + mt) * 256 + lane * 4]);
    }
    const ushort4* xpp0 = reinterpret_cast<const ushort4*>(&XPs[2 * STR + w * MT * 256 + lane * 4]);
    const ushort4* xpp1 = reinterpret_cast<const ushort4*>(&XPs[3 * STR + w * MT * 256 + lane * 4]);
    ushort4* outp0 = reinterpret_cast<ushort4*>(&Houts[w * MT * 256 + lane * 4]);
    ushort4* outp1 = reinterpret_cast<ushort4*>(&Houts[STR + w * MT * 256 + lane * 4]);

#define REC_STEP(T_, XPBUF, XPP, HRP, HWP, OUTP)                                   \
    {                                                                              \
        bf16x8 af[KC];                                                             \
        _Pragma("unroll")                                                          \
        for (int kc = 0; kc < KC; ++kc)                                            \
            af[kc] = *reinterpret_cast<const bf16x8*>(&HRP[rdo + kc * 512]);       \
        f32x4 acc[MT];                                                             \
        _Pragma("unroll")                                                          \
        for (int mt = 0; mt < MT; ++mt) {                                          \
            acc[mt][0] = b2f(XPBUF[mt].x);                                         \
            acc[mt][1] = b2f(XPBUF[mt].y);                                         \
            acc[mt][2] = b2f(XPBUF[mt].z);                                         \
            acc[mt][3] = b2f(XPBUF[mt].w);                                         \
        }                                                                          \
        if ((T_) + 2 < TT) {                                                       \
            _Pragma("unroll")                                                      \
            for (int mt = 0; mt < MT; ++mt) XPBUF[mt] = XPP[mt * 64];              \
            XPP += STR / 2;                                                        \
        }                                                                          \
        _Pragma("unroll")                                                          \
        for (int kc = 0; kc < KC; ++kc)                                            \
            _Pragma("unroll")                                                      \
            for (int mt = 0; mt < MT; ++mt)                                        \
                acc[mt] = __builtin_amdgcn_mfma_f32_16x16x32_bf16(wh[kc][mt],      \
                                                    af[kc], acc[mt], 0, 0, 0);     \
        _Pragma("unroll")                                                          \
        for (int mt = 0; mt < MT; ++mt) {                                          \
            ushort2 lo = pk2(fmaxf(acc[mt][0], 0.f), fmaxf(acc[mt][1], 0.f));      \
            ushort2 hi = pk2(fmaxf(acc[mt][2], 0.f), fmaxf(acc[mt][3], 0.f));      \
            ushort4 o; o.x = lo.x; o.y = lo.y; o.z = hi.x; o.w = hi.y;             \
            *reinterpret_cast<ushort4*>(&HWP[wro + mt * 256]) = o;                 \
            OUTP[mt * 64] = o;                                                     \
        }                                                                          \
        OUTP += STR / 2;                                                           \
        __builtin_amdgcn_s_waitcnt(0xC07F);                                        \
        __builtin_amdgcn_s_barrier();                                              \
    }

#pragma unroll 1
    for (int t = 0; t < TT; t += 2) {
        REC_STEP(t, xpA, xpp0, hr0, hw1, outp0)
        REC_STEP(t + 1, xpB, xpp1, hr1, hw0, outp1)
    }
#undef REC_STEP
}

// ---------------- final dense: out[b] = flat[b,:] . Wd + bd ----------------
// H1 is tile-layout (H=64): block per batch-slice s; thread tid <-> tile elem
// tid = (q4*16+l15)*4+r, i.e. (b = s*16+l15, c = q4*4+r). Coalesced reads.
__global__ __launch_bounds__(256) void dense_kernel(const unsigned short* __restrict__ Ht,
                                                    const float* __restrict__ Wd,
                                                    const float* __restrict__ bd,
                                                    float* __restrict__ out) {
    __shared__ float red[16][17];
    const int s = blockIdx.x;
    const int tid = threadIdx.x;
    const int q4 = tid >> 6, l15 = (tid >> 2) & 15, r = tid & 3;
    const int c = q4 * 4 + r;
    float acc = 0.f;
    for (int t = 0; t < TT; ++t) {
        const unsigned short* base = &Ht[((size_t)(s * TT + t) * 4) * 256];
#pragma unroll
        for (int kt = 0; kt < 4; ++kt)
            acc += b2f(base[kt * 256 + tid]) * Wd[t * 64 + kt * 16 + c];
    }
    red[l15][q4 * 4 + r] = acc;
    __syncthreads();
    if (tid < 16) {
        float sum = 0.f;
#pragma unroll
        for (int j = 0; j < 16; ++j) sum += red[tid][j];
        out[s * 16 + tid] = sum + bd[0];
    }
}

extern "C" void kernel_launch(void* const* d_in, const int* in_sizes, int n_in,
                              void* d_out, int out_size, void* d_ws, size_t ws_size,
                              hipStream_t stream) {
    (void)in_sizes; (void)n_in; (void)out_size; (void)ws_size;
    const float* x   = (const float*)d_in[0];
    const float* Wx1 = (const float*)d_in[1];
    const float* Wh1 = (const float*)d_in[2];
    const float* b1  = (const float*)d_in[3];
    const float* Wx2 = (const float*)d_in[4];
    const float* Wh2 = (const float*)d_in[5];
    const float* b2  = (const float*)d_in[6];
    const float* Wx3 = (const float*)d_in[7];
    const float* Wh3 = (const float*)d_in[8];
    const float* b3  = (const float*)d_in[9];
    const float* Wx4 = (const float*)d_in[10];
    const float* Wh4 = (const float*)d_in[11];
    const float* b4  = (const float*)d_in[12];
    const float* Wd  = (const float*)d_in[13];
    const float* bd  = (const float*)d_in[14];
    float* out = (float*)d_out;

    char* ws = (char*)d_ws;
    unsigned short* xb = (unsigned short*)(ws);
    unsigned short* XP = (unsigned short*)(ws + 16777216);
    unsigned short* H0 = (unsigned short*)(ws + 16777216 + 67108864);
    unsigned short* H1 = (unsigned short*)(ws + 16777216 + 2 * 67108864);

    cvt_kernel<<<8192, 256, 0, stream>>>(x, xb, BB * TT * 64 / 4);

    gemm_xp<64, 128, 0><<<1024, 256, 0, stream>>>(xb, Wx1, b1, XP);
    rec_cp<128><<<16, 512, 0, stream>>>(XP, Wh1, H0);

    gemm_xp<128, 256, 1><<<1024, 256, 0, stream>>>(H0, Wx2, b2, XP);
    rec_cp<256><<<16, 512, 0, stream>>>(XP, Wh2, H1);

    gemm_xp<256, 128, 1><<<1024, 256, 0, stream>>>(H1, Wx3, b3, XP);
    rec_cp<128><<<16, 512, 0, stream>>>(XP, Wh3, H0);

    gemm_xp<128, 64, 1><<<1024, 256, 0, stream>>>(H0, Wx4, b4, XP);
    rec_cp<64><<<16, 512, 0, stream>>>(XP, Wh4, H1);

    dense_kernel<<<32, 256, 0, stream>>>(H1, Wd, bd, out);
}

// Round 11
// 575.508 us; speedup vs baseline: 1.4096x; 1.4096x over previous
//
#include <hip/hip_runtime.h>
#include <hip/hip_bf16.h>

#define BB 512
#define TT 256

typedef __attribute__((ext_vector_type(8))) short bf16x8;
typedef __attribute__((ext_vector_type(4))) float f32x4;

__device__ __forceinline__ unsigned short f2b(float f) {
    union { float f; unsigned u; } v; v.f = f;
    unsigned r = v.u + 0x7FFFu + ((v.u >> 16) & 1u);
    return (unsigned short)(r >> 16);
}
__device__ __forceinline__ float b2f(unsigned short h) {
    union { unsigned u; float f; } v; v.u = ((unsigned)h) << 16;
    return v.f;
}
// packed f32x2 -> bf16x2 (v_cvt_pk_bf16_f32, RNE — bit-compatible with f2b)
__device__ __forceinline__ ushort2 pk2(float a, float b) {
    __hip_bfloat162 h = __float22bfloat162_rn(float2{a, b});
    union { __hip_bfloat162 h; ushort2 u; } v; v.h = h; return v.u;
}

// ======================================================================
// GLOBAL hidden-state layout ("B-layout"): per (s,t), a 16-batch x K block
// of shorts at addr(b,k) = (k>>3)*128 + b*8 + (k&7). This is exactly the
// LDS layout proven in rounds 8-9:
//   consumer B-frag (k-chunk kc) = ONE b128 at  kc*512 + quad*128 + l15*8
//   producer write (col-tile mt) = ushort4  at  wro + mt*256,
//     wro = ((colbase>>3)+(quad>>1))*128 + l15*8 + (quad&1)*4
// Both fully coalesced.
// ======================================================================

// ---------------- fp32 x -> bf16 B-layout tiles ----------------
// block = one (s,t): 256 threads write 16x64 block (1024 shorts).
// thread tid covers b=(tid>>1)&15, f = (tid>>5)*8 + (tid&1)*4 + r.
__global__ __launch_bounds__(256) void cvt_tile(const float* __restrict__ x,
                                                unsigned short* __restrict__ xb) {
    const int blk = blockIdx.x;            // s*256 + t
    const int s = blk >> 8, t = blk & 255;
    const int tid = threadIdx.x;
    const int b = (tid >> 1) & 15;
    const int f0 = (tid >> 5) * 8 + (tid & 1) * 4;
    float4 v = *reinterpret_cast<const float4*>(
        &x[(((size_t)(s * 16 + b) * TT) + t) * 64 + f0]);
    ushort2 lo = pk2(v.x, v.y), hi = pk2(v.z, v.w);
    ushort4 o; o.x = lo.x; o.y = lo.y; o.z = hi.x; o.w = hi.y;
    *reinterpret_cast<ushort4*>(&xb[(size_t)blk * 1024 + tid * 4]) = o;
}

// ---------------- fused recurrence ----------------
// h_t = relu(bias + h_in(t)·Wx + h_{t-1}·Wh)   [input projection fused]
// 32 blocks x 256 thr (4 waves), col-partitioned. Wx^T and Wh^T A-frags
// VGPR-stationary. h_in(t) B-frags: global b128 loads, 2-step prefetch in
// two parity buffers (no end-of-step reg copies). Own h: LDS ping-pong
// (B-layout) + global store in B-layout straight from epilogue regs.
// Wx MFMAs issue first (register operands) to execute under ds_read latency
// of the Wh af-frags. Barrier = builtin lgkm-only waitcnt + s_barrier.
template<int H, int KX>
__global__ __launch_bounds__(256, 1) void rec_f(const unsigned short* __restrict__ Hin,
                                                const float* __restrict__ Wx,
                                                const float* __restrict__ Wh,
                                                const float* __restrict__ bias,
                                                unsigned short* __restrict__ Hout) {
    constexpr int KC   = H / 32;
    constexpr int KCX  = KX / 32;
    constexpr int MT   = H / 64;
    constexpr int STRH = 16 * H;    // shorts per step (out)
    constexpr int STRX = 16 * KX;   // shorts per step (in)
    __shared__ __align__(16) unsigned short hbuf[2][16 * H];
    const int tid = threadIdx.x;
    const int s = blockIdx.x;
    const int w = tid >> 6;
    const int lane = tid & 63;
    const int l15 = lane & 15;
    const int quad = lane >> 4;
    const int colbase = w * (H / 4);

    // stationary A-fragments (fp32 global -> bf16, once)
    bf16x8 wh[KC][MT], wx[KCX][MT];
#pragma unroll
    for (int mt = 0; mt < MT; ++mt) {
        int m = colbase + mt * 16 + l15;
#pragma unroll
        for (int kc = 0; kc < KC; ++kc)
#pragma unroll
            for (int j = 0; j < 8; ++j)
                wh[kc][mt][j] = (short)f2b(Wh[(kc * 32 + quad * 8 + j) * H + m]);
#pragma unroll
        for (int kx = 0; kx < KCX; ++kx)
#pragma unroll
            for (int j = 0; j < 8; ++j)
                wx[kx][mt][j] = (short)f2b(Wx[(kx * 32 + quad * 8 + j) * H + m]);
    }
    // bias regs: acc[mt][r] covers col colbase + mt*16 + quad*4 + r
    f32x4 bv[MT];
#pragma unroll
    for (int mt = 0; mt < MT; ++mt) {
        float4 b4v = reinterpret_cast<const float4*>(bias)[(colbase >> 2) + mt * 4 + quad];
        bv[mt][0] = b4v.x; bv[mt][1] = b4v.y; bv[mt][2] = b4v.z; bv[mt][3] = b4v.w;
    }

    for (int i = tid; i < 16 * H; i += 256) hbuf[0][i] = 0;
    __syncthreads();

    const unsigned short* Hins = Hin + (size_t)s * TT * STRX;
    unsigned short* Houts = Hout + (size_t)s * TT * STRH;
    const int rdo = quad * 128 + l15 * 8;
    const int wro = ((colbase >> 3) + (quad >> 1)) * 128 + l15 * 8 + (quad & 1) * 4;

    // parity input-frag buffers: A = even t, B = odd t; reloaded 2 ahead
    bf16x8 inA[KCX], inB[KCX];
#pragma unroll
    for (int kx = 0; kx < KCX; ++kx) {
        inA[kx] = *reinterpret_cast<const bf16x8*>(&Hins[kx * 512 + rdo]);
        inB[kx] = *reinterpret_cast<const bf16x8*>(&Hins[STRX + kx * 512 + rdo]);
    }
    const unsigned short* inp0 = Hins + 2 * STRX + rdo;
    const unsigned short* inp1 = Hins + 3 * STRX + rdo;
    unsigned short* outp0 = Houts + wro;
    unsigned short* outp1 = Houts + STRH + wro;

#define REC_STEP(T_, INB, INP, HRP, HWP, OUTP)                                     \
    {                                                                              \
        bf16x8 af[KC];                                                             \
        _Pragma("unroll")                                                          \
        for (int kc = 0; kc < KC; ++kc)                                            \
            af[kc] = *reinterpret_cast<const bf16x8*>(&HRP[rdo + kc * 512]);       \
        f32x4 acc[MT];                                                             \
        _Pragma("unroll")                                                          \
        for (int mt = 0; mt < MT; ++mt) acc[mt] = bv[mt];                          \
        _Pragma("unroll")                                                          \
        for (int kx = 0; kx < KCX; ++kx)                                           \
            _Pragma("unroll")                                                      \
            for (int mt = 0; mt < MT; ++mt)                                        \
                acc[mt] = __builtin_amdgcn_mfma_f32_16x16x32_bf16(wx[kx][mt],      \
                                                    INB[kx], acc[mt], 0, 0, 0);    \
        if ((T_) + 2 < TT) {                                                       \
            _Pragma("unroll")                                                      \
            for (int kx = 0; kx < KCX; ++kx)                                       \
                INB[kx] = *reinterpret_cast<const bf16x8*>(&INP[kx * 512]);        \
            INP += 2 * STRX;                                                       \
        }                                                                          \
        _Pragma("unroll")                                                          \
        for (int kc = 0; kc < KC; ++kc)                                            \
            _Pragma("unroll")                                                      \
            for (int mt = 0; mt < MT; ++mt)                                        \
                acc[mt] = __builtin_amdgcn_mfma_f32_16x16x32_bf16(wh[kc][mt],      \
                                                    af[kc], acc[mt], 0, 0, 0);     \
        _Pragma("unroll")                                                          \
        for (int mt = 0; mt < MT; ++mt) {                                          \
            ushort2 lo = pk2(fmaxf(acc[mt][0], 0.f), fmaxf(acc[mt][1], 0.f));      \
            ushort2 hi = pk2(fmaxf(acc[mt][2], 0.f), fmaxf(acc[mt][3], 0.f));      \
            ushort4 o; o.x = lo.x; o.y = lo.y; o.z = hi.x; o.w = hi.y;             \
            *reinterpret_cast<ushort4*>(&HWP[wro + mt * 256]) = o;                 \
            *reinterpret_cast<ushort4*>(OUTP + mt * 256) = o;                      \
        }                                                                          \
        OUTP += 2 * STRH;                                                          \
        __builtin_amdgcn_s_waitcnt(0xC07F);                                        \
        __builtin_amdgcn_s_barrier();                                              \
    }

#pragma unroll 1
    for (int t = 0; t < TT; t += 2) {
        REC_STEP(t, inA, inp0, (&hbuf[0][0]), (&hbuf[1][0]), outp0)
        REC_STEP(t + 1, inB, inp1, (&hbuf[1][0]), (&hbuf[0][0]), outp1)
    }
#undef REC_STEP
}

// ---------------- final dense: out[b] = flat[b,:] . Wd + bd ----------------
// Ht in B-layout (K=64): thread tid reads ushort4 at tid*4 per (s,t) block:
// b=(tid>>1)&15, k=(tid>>5)*8+(tid&1)*4+r. Coalesced.
__global__ __launch_bounds__(256) void dense_kernel(const unsigned short* __restrict__ Ht,
                                                    const float* __restrict__ Wd,
                                                    const float* __restrict__ bd,
                                                    float* __restrict__ out) {
    __shared__ float red[16][17];
    const int s = blockIdx.x;
    const int tid = threadIdx.x;
    const int b = (tid >> 1) & 15;
    const int kbase = (tid >> 5) * 8 + (tid & 1) * 4;
    const unsigned short* base = Ht + (size_t)s * TT * 1024 + tid * 4;
    float acc = 0.f;
    for (int t = 0; t < TT; ++t) {
        ushort4 v = *reinterpret_cast<const ushort4*>(base + (size_t)t * 1024);
        const float* wd = &Wd[t * 64 + kbase];
        acc += b2f(v.x) * wd[0] + b2f(v.y) * wd[1] + b2f(v.z) * wd[2] + b2f(v.w) * wd[3];
    }
    red[b][(tid >> 5) * 2 + (tid & 1)] = acc;
    __syncthreads();
    if (tid < 16) {
        float sum = 0.f;
#pragma unroll
        for (int j = 0; j < 16; ++j) sum += red[tid][j];
        out[s * 16 + tid] = sum + bd[0];
    }
}

extern "C" void kernel_launch(void* const* d_in, const int* in_sizes, int n_in,
                              void* d_out, int out_size, void* d_ws, size_t ws_size,
                              hipStream_t stream) {
    (void)in_sizes; (void)n_in; (void)out_size; (void)ws_size;
    const float* x   = (const float*)d_in[0];
    const float* Wx1 = (const float*)d_in[1];
    const float* Wh1 = (const float*)d_in[2];
    const float* b1  = (const float*)d_in[3];
    const float* Wx2 = (const float*)d_in[4];
    const float* Wh2 = (const float*)d_in[5];
    const float* b2  = (const float*)d_in[6];
    const float* Wx3 = (const float*)d_in[7];
    const float* Wh3 = (const float*)d_in[8];
    const float* b3  = (const float*)d_in[9];
    const float* Wx4 = (const float*)d_in[10];
    const float* Wh4 = (const float*)d_in[11];
    const float* b4  = (const float*)d_in[12];
    const float* Wd  = (const float*)d_in[13];
    const float* bd  = (const float*)d_in[14];
    float* out = (float*)d_out;

    char* ws = (char*)d_ws;
    // xbT 16.8M | HB0 67.1M | HB1 67.1M
    unsigned short* xbT = (unsigned short*)(ws);
    unsigned short* HB0 = (unsigned short*)(ws + 16777216);
    unsigned short* HB1 = (unsigned short*)(ws + 16777216 + 67108864);

    cvt_tile<<<8192, 256, 0, stream>>>(x, xbT);

    rec_f<128, 64><<<32, 256, 0, stream>>>(xbT, Wx1, Wh1, b1, HB0);
    rec_f<256, 128><<<32, 256, 0, stream>>>(HB0, Wx2, Wh2, b2, HB1);
    rec_f<128, 256><<<32, 256, 0, stream>>>(HB1, Wx3, Wh3, b3, HB0);
    rec_f<64, 128><<<32, 256, 0, stream>>>(HB0, Wx4, Wh4, b4, HB1);

    dense_kernel<<<32, 256, 0, stream>>>(HB1, Wd, bd, out);
}